// Round 9
// baseline (2657.244 us; speedup 1.0000x reference)
//
#include <hip/hip_runtime.h>

#define N_ROWS 16384
#define OBS    1024
#define HID    2048
#define LAT    256
#define VOCAB  8192
#define HQ     4
#define LN_EPS 1e-5f

typedef unsigned short u16;
typedef unsigned long long u64;
typedef __bf16 bf16x8 __attribute__((ext_vector_type(8)));
typedef float  f32x4  __attribute__((ext_vector_type(4)));

static __device__ __forceinline__ unsigned int float_to_ordered(float f) {
    unsigned int u = __float_as_uint(f);
    return (u & 0x80000000u) ? ~u : (u | 0x80000000u);
}
// fp32 -> bf16 round-to-nearest-even
static __device__ __forceinline__ u16 f2bf(float f) {
    unsigned int u = __float_as_uint(f);
    unsigned int r = u + 0x7FFFu + ((u >> 16) & 1u);
    return (u16)(r >> 16);
}
static __device__ __forceinline__ float bf2f(u16 u) {
    return __uint_as_float((unsigned int)u << 16);
}

#define GL2LDS(gp, lp) __builtin_amdgcn_global_load_lds( \
    (const __attribute__((address_space(1))) void*)(gp), \
    (__attribute__((address_space(3))) void*)(lp), 16, 0, 0)

// ---------------------------------------------------------------------------
// bf16 MFMA GEMM, 128x128 tile, C = A @ B^T + bias. (verified rounds 3-8)
// EPI 0: store bf16 C.  1: relu + store bf16 C.  3: fused loss, no store.
// ---------------------------------------------------------------------------
template<int EPI>
__global__ __launch_bounds__(256, 4) void mfma_gemm_k(
    const u16* __restrict__ Abf, const u16* __restrict__ Bbf,
    const float* __restrict__ bias,
    u16* __restrict__ Cbf,
    const float* __restrict__ X, double* __restrict__ lacc,
    int K, int Nd)
{
    __shared__ u16 As[128 * 64];
    __shared__ u16 Bs[128 * 64];

    const int tid  = threadIdx.x;
    const int wv   = tid >> 6, lane = tid & 63;
    const int wm   = wv & 1,   wn   = wv >> 1;
    const int m_   = lane & 15, g   = lane >> 4;
    const int m0   = blockIdx.x * 128;
    const int n0   = blockIdx.y * 128;

    f32x4 acc[4][4];
#pragma unroll
    for (int i = 0; i < 4; ++i)
#pragma unroll
        for (int j = 0; j < 4; ++j)
            acc[i][j] = f32x4{0.f, 0.f, 0.f, 0.f};

    const u16* Ablk = Abf + (size_t)m0 * K;
    const u16* Bblk = Bbf + (size_t)n0 * K;

    for (int k0 = 0; k0 < K; k0 += 64) {
#pragma unroll
        for (int c = 0; c < 4; ++c) {
            const int ci = (wv * 4 + c) * 64 + lane;
            const int r  = ci >> 3;
            const int cc = ci & 7;
            const int kc = (cc ^ (r & 7)) << 3;
            GL2LDS(Ablk + (size_t)r * K + k0 + kc, As + (wv * 4 + c) * 512);
            GL2LDS(Bblk + (size_t)r * K + k0 + kc, Bs + (wv * 4 + c) * 512);
        }
        __syncthreads();
#pragma unroll
        for (int ks = 0; ks < 2; ++ks) {
            const int ccw = ks * 4 + g;
            const int sw  = (ccw ^ (m_ & 7)) << 3;
            bf16x8 af[4], bfr[4];
#pragma unroll
            for (int t = 0; t < 4; ++t) {
                af[t]  = *(const bf16x8*)&As[(wm * 64 + t * 16 + m_) * 64 + sw];
                bfr[t] = *(const bf16x8*)&Bs[(wn * 64 + t * 16 + m_) * 64 + sw];
            }
#pragma unroll
            for (int mi = 0; mi < 4; ++mi)
#pragma unroll
                for (int ni = 0; ni < 4; ++ni)
                    acc[mi][ni] = __builtin_amdgcn_mfma_f32_16x16x32_bf16(
                        af[mi], bfr[ni], acc[mi][ni], 0, 0, 0);
        }
        __syncthreads();
    }

    float bs[4];
#pragma unroll
    for (int ni = 0; ni < 4; ++ni) bs[ni] = bias[n0 + wn * 64 + ni * 16 + m_];

    if constexpr (EPI == 3) {
        float lsum = 0.f;
#pragma unroll
        for (int mi = 0; mi < 4; ++mi)
#pragma unroll
            for (int j = 0; j < 4; ++j) {
                const int row = m0 + wm * 64 + mi * 16 + g * 4 + j;
#pragma unroll
                for (int ni = 0; ni < 4; ++ni) {
                    const int col = n0 + wn * 64 + ni * 16 + m_;
                    float r = acc[mi][ni][j] + bs[ni] - X[(size_t)row * Nd + col];
                    lsum = fmaf(r, r, lsum);
                }
            }
#pragma unroll
        for (int off = 32; off >= 1; off >>= 1) lsum += __shfl_xor(lsum, off);
        __shared__ float red[4];
        if (lane == 0) red[wv] = lsum;
        __syncthreads();
        if (tid == 0)
            atomicAdd(lacc, (double)(red[0] + red[1] + red[2] + red[3]));
    } else {
#pragma unroll
        for (int mi = 0; mi < 4; ++mi)
#pragma unroll
            for (int j = 0; j < 4; ++j) {
                const int row = m0 + wm * 64 + mi * 16 + g * 4 + j;
#pragma unroll
                for (int ni = 0; ni < 4; ++ni) {
                    const int col = n0 + wn * 64 + ni * 16 + m_;
                    float v = acc[mi][ni][j] + bs[ni];
                    if constexpr (EPI == 1) v = fmaxf(v, 0.f);
                    Cbf[(size_t)row * Nd + col] = f2bf(v);
                }
            }
    }
}

// ---------------------------------------------------------------------------
// GEMM2 dedicated kernel: 64x64 tile (1024 blocks = 4/CU).
// latent = h @ w2T^T + b2; writes fp32 latent + fp32 resid + bf16 rbf.
// ---------------------------------------------------------------------------
__global__ __launch_bounds__(256, 4) void gemm2_k(
    const u16* __restrict__ Abf, const u16* __restrict__ Bbf,
    const float* __restrict__ bias,
    float* __restrict__ lat, float* __restrict__ resid, u16* __restrict__ rbf)
{
    __shared__ u16 As[64 * 64];
    __shared__ u16 Bs[64 * 64];

    const int tid = threadIdx.x;
    const int wv  = tid >> 6, lane = tid & 63;
    const int wm  = wv & 1,   wn   = wv >> 1;
    const int m_  = lane & 15, g   = lane >> 4;
    const int m0  = blockIdx.x * 64;
    const int n0  = blockIdx.y * 64;

    f32x4 acc[2][2];
#pragma unroll
    for (int i = 0; i < 2; ++i)
#pragma unroll
        for (int j = 0; j < 2; ++j)
            acc[i][j] = f32x4{0.f, 0.f, 0.f, 0.f};

    const u16* Ablk = Abf + (size_t)m0 * HID;
    const u16* Bblk = Bbf + (size_t)n0 * HID;

    for (int k0 = 0; k0 < HID; k0 += 64) {
#pragma unroll
        for (int c = 0; c < 2; ++c) {
            const int ci = (wv * 2 + c) * 64 + lane;
            const int r  = ci >> 3;
            const int cc = ci & 7;
            const int kc = (cc ^ (r & 7)) << 3;
            GL2LDS(Ablk + (size_t)r * HID + k0 + kc, As + (wv * 2 + c) * 512);
            GL2LDS(Bblk + (size_t)r * HID + k0 + kc, Bs + (wv * 2 + c) * 512);
        }
        __syncthreads();
#pragma unroll
        for (int ks = 0; ks < 2; ++ks) {
            const int ccw = ks * 4 + g;
            const int sw  = (ccw ^ (m_ & 7)) << 3;
            bf16x8 af[2], bfr[2];
#pragma unroll
            for (int t = 0; t < 2; ++t) {
                af[t]  = *(const bf16x8*)&As[(wm * 32 + t * 16 + m_) * 64 + sw];
                bfr[t] = *(const bf16x8*)&Bs[(wn * 32 + t * 16 + m_) * 64 + sw];
            }
#pragma unroll
            for (int mi = 0; mi < 2; ++mi)
#pragma unroll
                for (int ni = 0; ni < 2; ++ni)
                    acc[mi][ni] = __builtin_amdgcn_mfma_f32_16x16x32_bf16(
                        af[mi], bfr[ni], acc[mi][ni], 0, 0, 0);
        }
        __syncthreads();
    }

#pragma unroll
    for (int mi = 0; mi < 2; ++mi)
#pragma unroll
        for (int j = 0; j < 4; ++j) {
            const int row = m0 + wm * 32 + mi * 16 + g * 4 + j;
#pragma unroll
            for (int ni = 0; ni < 2; ++ni) {
                const int col = n0 + wn * 32 + ni * 16 + m_;
                float v = acc[mi][ni][j] + bias[col];
                lat  [(size_t)row * LAT + col] = v;
                resid[(size_t)row * LAT + col] = v;
                rbf  [(size_t)row * LAT + col] = f2bf(v);
            }
        }
}

// ---------------------------------------------------------------------------
// All 4 weight transposes in ONE launch: W fp32 [K,N] -> Wt bf16 [N,K].
// ---------------------------------------------------------------------------
__global__ __launch_bounds__(256) void tpose4_k(
    const float* __restrict__ W0, u16* __restrict__ T0,
    const float* __restrict__ W1, u16* __restrict__ T1,
    const float* __restrict__ W2, u16* __restrict__ T2,
    const float* __restrict__ W3, u16* __restrict__ T3)
{
    __shared__ u16 t[32][33];
    const int bid = blockIdx.x;
    const float* W; u16* T; int K, N, r;
    if (bid < 2048)      { W = W0; T = T0; K = OBS; N = HID; r = bid; }
    else if (bid < 2560) { W = W1; T = T1; K = HID; N = LAT; r = bid - 2048; }
    else if (bid < 3072) { W = W2; T = T2; K = LAT; N = HID; r = bid - 2560; }
    else                 { W = W3; T = T3; K = HID; N = OBS; r = bid - 3072; }
    const int nb = N >> 5;
    const int n0 = (r % nb) * 32, k0 = (r / nb) * 32;
    const int lx = threadIdx.x & 31, ly = threadIdx.x >> 5;
#pragma unroll
    for (int i = 0; i < 4; ++i)
        t[ly + 8 * i][lx] = f2bf(W[(size_t)(k0 + ly + 8 * i) * N + n0 + lx]);
    __syncthreads();
#pragma unroll
    for (int i = 0; i < 4; ++i)
        T[(size_t)(n0 + ly + 8 * i) * K + k0 + lx] = t[lx][ly + 8 * i];
}

// ---------------------------------------------------------------------------
// LayerNorm + ReLU in place on bf16 h (fp32 math), one block per row of 2048.
// ---------------------------------------------------------------------------
__device__ __forceinline__ float block_reduce_bcast(float v, float* scratch) {
#pragma unroll
    for (int off = 32; off >= 1; off >>= 1) v += __shfl_xor(v, off);
    const int tid = threadIdx.x;
    __syncthreads();
    if ((tid & 63) == 0) scratch[tid >> 6] = v;
    __syncthreads();
    return scratch[0] + scratch[1] + scratch[2] + scratch[3];
}

__global__ __launch_bounds__(256) void ln_relu_bf_k(
    u16* __restrict__ h, const float* __restrict__ g, const float* __restrict__ b)
{
    __shared__ float scratch[4];
    const int tid = threadIdx.x;
    u16* hp = h + (size_t)blockIdx.x * HID + tid * 8;

    ushort4 r0 = *(const ushort4*)hp;
    ushort4 r1 = *(const ushort4*)(hp + 4);
    float v[8] = {bf2f(r0.x), bf2f(r0.y), bf2f(r0.z), bf2f(r0.w),
                  bf2f(r1.x), bf2f(r1.y), bf2f(r1.z), bf2f(r1.w)};

    float s = 0.f;
#pragma unroll
    for (int e = 0; e < 8; ++e) s += v[e];
    const float mu = block_reduce_bcast(s, scratch) * (1.f / HID);

    float vs = 0.f;
#pragma unroll
    for (int e = 0; e < 8; ++e) { float d = v[e] - mu; vs = fmaf(d, d, vs); }
    const float var = block_reduce_bcast(vs, scratch) * (1.f / HID);
    const float rs = rsqrtf(var + LN_EPS);

    ushort4 o0, o1;
#pragma unroll
    for (int e = 0; e < 8; ++e) {
        const int col = tid * 8 + e;
        float w = (v[e] - mu) * rs * g[col] + b[col];
        w = fmaxf(w, 0.f);
        u16 bb = f2bf(w);
        if (e < 4) ((u16*)&o0)[e] = bb; else ((u16*)&o1)[e - 4] = bb;
    }
    *(ushort4*)hp = o0;
    *(ushort4*)(hp + 4) = o1;
}

// ---------------------------------------------------------------------------
// Fused codebook pass: exact fp32 norms + bf16(-2E) copy + keys/accs/cnt init.
// grid = HQ*VOCAB/4 = 8192 blocks; blocks 0..63 init keys; 64 inits accs;
// 65,66 zero the per-(level,m0) done-counters.
// ---------------------------------------------------------------------------
__global__ __launch_bounds__(256) void enorm_k(
    const float* __restrict__ cb, float* __restrict__ enorm,
    u16* __restrict__ cbb, u64* __restrict__ keys, double* __restrict__ accs,
    int* __restrict__ cnt)
{
    if (blockIdx.x < 64) keys[blockIdx.x * 256 + threadIdx.x] = ~0ull;
    if (blockIdx.x == 64 && threadIdx.x < 2) accs[threadIdx.x] = 0.0;
    if (blockIdx.x == 65) cnt[threadIdx.x] = 0;
    if (blockIdx.x == 66) cnt[256 + threadIdx.x] = 0;
    const int row  = blockIdx.x * 4 + (threadIdx.x >> 6);
    const int lane = threadIdx.x & 63;
    const size_t off = (size_t)row * LAT + lane * 4;
    float4 v = *(const float4*)(cb + off);
    ushort4 o;
    o.x = f2bf(-2.f * v.x); o.y = f2bf(-2.f * v.y);
    o.z = f2bf(-2.f * v.z); o.w = f2bf(-2.f * v.w);
    *(ushort4*)(cbb + off) = o;
    float s = v.x * v.x + v.y * v.y + v.z * v.z + v.w * v.w;
#pragma unroll
    for (int off2 = 32; off2 >= 1; off2 >>= 1) s += __shfl_xor(s, off2);
    if (lane == 0) enorm[row] = s;
}

// fp32 -> bf16 bulk convert (4 elems/thread)
__global__ __launch_bounds__(256) void f2bf_k(
    const float* __restrict__ in, u16* __restrict__ out)
{
    size_t i = ((size_t)blockIdx.x * 256 + threadIdx.x) * 4;
    float4 v = *(const float4*)(in + i);
    ushort4 o;
    o.x = f2bf(v.x); o.y = f2bf(v.y); o.z = f2bf(v.z); o.w = f2bf(v.w);
    *(ushort4*)(out + i) = o;
}

// ---------------------------------------------------------------------------
// Distance + argmin via bf16 MFMA (round-6 core, proven 113 us) with the
// vq_update FUSED into the tail via last-block-done:
//  * each block: atomicMin keys -> threadfence -> counter atomicAdd(cnt[m0b])
//  * the 64th (last) column-block for m0 becomes the updater for rows
//    m0..m0+127: atomic-reads final keys (device-coherent RMW read, G16),
//    gathers fp32 codes, updates resid/rbf (or writes qbf on LAST level),
//    accumulates sum(resid_new^2), resets keys for the next level.
//  Safety: the only readers of rbf rows m0 are the 64 blocks that increment
//  cnt[m0b], all done before the updater runs; cross-kernel visibility via
//  kernel boundaries; counters zeroed per launch in enorm_k.
// ---------------------------------------------------------------------------
template<bool LAST>
__global__ __launch_bounds__(256, 4) void dist_mfma_k(
    const u16* __restrict__ Abf, const u16* __restrict__ Bneg2,
    const float* __restrict__ enorm, u64* __restrict__ keys,
    float* __restrict__ resid, u16* __restrict__ aux,   // rbf or qbf
    const float* __restrict__ latent, const float* __restrict__ Ecb,
    int* __restrict__ cnt, double* __restrict__ accs)
{
    __shared__ u16 As[128 * 64];
    __shared__ u16 Bs[128 * 64];
    __shared__ u64 shk[128][2];
    __shared__ int sidx[128];
    __shared__ int sflag;
    __shared__ float red[4];

    const int tid  = threadIdx.x;
    const int wv   = tid >> 6, lane = tid & 63;
    const int wm   = wv & 1,   wn   = wv >> 1;
    const int m_   = lane & 15, g   = lane >> 4;
    const int m0   = blockIdx.x * 128;
    const int n0   = blockIdx.y * 128;

    f32x4 acc[4][4];
#pragma unroll
    for (int ni = 0; ni < 4; ++ni) {
        const float en = enorm[n0 + wn * 64 + ni * 16 + m_];
#pragma unroll
        for (int mi = 0; mi < 4; ++mi)
            acc[mi][ni] = f32x4{en, en, en, en};
    }

    const u16* Ablk = Abf   + (size_t)m0 * LAT;
    const u16* Bblk = Bneg2 + (size_t)n0 * LAT;

    for (int k0 = 0; k0 < LAT; k0 += 64) {
#pragma unroll
        for (int c = 0; c < 4; ++c) {
            const int ci = (wv * 4 + c) * 64 + lane;
            const int r  = ci >> 3;
            const int cc = ci & 7;
            const int kc = (cc ^ (r & 7)) << 3;
            GL2LDS(Ablk + (size_t)r * LAT + k0 + kc, As + (wv * 4 + c) * 512);
            GL2LDS(Bblk + (size_t)r * LAT + k0 + kc, Bs + (wv * 4 + c) * 512);
        }
        __syncthreads();
#pragma unroll
        for (int ks = 0; ks < 2; ++ks) {
            const int ccw = ks * 4 + g;
            const int sw  = (ccw ^ (m_ & 7)) << 3;
            bf16x8 af[4], bfr[4];
#pragma unroll
            for (int t = 0; t < 4; ++t) {
                af[t]  = *(const bf16x8*)&As[(wm * 64 + t * 16 + m_) * 64 + sw];
                bfr[t] = *(const bf16x8*)&Bs[(wn * 64 + t * 16 + m_) * 64 + sw];
            }
#pragma unroll
            for (int mi = 0; mi < 4; ++mi)
#pragma unroll
                for (int ni = 0; ni < 4; ++ni)
                    acc[mi][ni] = __builtin_amdgcn_mfma_f32_16x16x32_bf16(
                        af[mi], bfr[ni], acc[mi][ni], 0, 0, 0);
        }
        __syncthreads();
    }

#pragma unroll
    for (int mi = 0; mi < 4; ++mi)
#pragma unroll
        for (int j = 0; j < 4; ++j) {
            float bs_ = acc[mi][0][j];
            int   bi_ = n0 + wn * 64 + m_;
#pragma unroll
            for (int ni = 1; ni < 4; ++ni) {
                const float s = acc[mi][ni][j];
                const int   v = n0 + wn * 64 + ni * 16 + m_;
                if (s < bs_) { bs_ = s; bi_ = v; }
            }
            u64 best = ((u64)float_to_ordered(bs_) << 32) | (unsigned)bi_;
#pragma unroll
            for (int mask = 1; mask <= 8; mask <<= 1) {
                u64 o = __shfl_xor(best, mask);
                best = o < best ? o : best;
            }
            if (m_ == 0) shk[wm * 64 + mi * 16 + g * 4 + j][wn] = best;
        }
    __syncthreads();
    if (tid < 128) {
        u64 a = shk[tid][0], b = shk[tid][1];
        atomicMin(&keys[m0 + tid], a < b ? a : b);
    }
    __threadfence();
    __syncthreads();
    if (tid == 0) sflag = atomicAdd(&cnt[blockIdx.x], 1);
    __syncthreads();
    if (sflag != 63) return;

    // ---- fused vq_update: this block is the last for m0 ----
    if (tid < 128) {
        u64 k = atomicAdd(&keys[m0 + tid], 0ull);   // coherent read
        sidx[tid] = (int)(k & 0xFFFFFFFFull);
        if (!LAST) keys[m0 + tid] = ~0ull;          // reset for next level
    }
    __syncthreads();
    float lsum = 0.f;
    for (int r = 0; r < 128; ++r) {
        const int row = m0 + r;
        const float q = Ecb[(size_t)sidx[r] * LAT + tid];
        float v = resid[(size_t)row * LAT + tid] - q;
        if constexpr (LAST) {
            aux[(size_t)row * LAT + tid] =
                f2bf(latent[(size_t)row * LAT + tid] - v);
        } else {
            resid[(size_t)row * LAT + tid] = v;
            aux[(size_t)row * LAT + tid] = f2bf(v);
        }
        lsum = fmaf(v, v, lsum);
    }
#pragma unroll
    for (int off = 32; off >= 1; off >>= 1) lsum += __shfl_xor(lsum, off);
    if ((tid & 63) == 0) red[tid >> 6] = lsum;
    __syncthreads();
    if (tid == 0)
        atomicAdd(accs, (double)(red[0] + red[1] + red[2] + red[3]));
}

__global__ void finalize_k(const double* __restrict__ acc, float* __restrict__ out) {
    double total = 1.5 * acc[0] / (double)((size_t)N_ROWS * LAT)
                 + 0.5 * acc[1] / (double)((size_t)N_ROWS * OBS);
    out[0] = (float)total;
}

// ---------------------------------------------------------------------------
extern "C" void kernel_launch(void* const* d_in, const int* in_sizes, int n_in,
                              void* d_out, int out_size, void* d_ws, size_t ws_size,
                              hipStream_t stream)
{
    const float* x      = (const float*)d_in[0];
    const float* cb     = (const float*)d_in[1];
    const float* enc_w1 = (const float*)d_in[2];
    const float* enc_b1 = (const float*)d_in[3];
    const float* ln_g   = (const float*)d_in[4];
    const float* ln_b   = (const float*)d_in[5];
    const float* enc_w2 = (const float*)d_in[6];
    const float* enc_b2 = (const float*)d_in[7];
    const float* dec_w1 = (const float*)d_in[8];
    const float* dec_b1 = (const float*)d_in[9];
    const float* dec_w2 = (const float*)d_in[10];
    const float* dec_b2 = (const float*)d_in[11];

    char* ws = (char*)d_ws;
    const size_t MB = 1ull << 20;
    u16* hbuf = (u16*)ws;                          // 0-64MB: h_bf then dh_bf
    u16* cbb  = (u16*)(ws + 64 * MB);              // -2E bf16, live all launch
    u16* rbf  = (u16*)(ws + 80 * MB);
    u16* qbf  = (u16*)(ws + 88 * MB);
    u16* xbf  = (u16*)(ws + 96 * MB);              // overlaps latent (dead by GEMM2)
    float* latent = (float*)(ws + 96 * MB);
    float* resid  = (float*)(ws + 112 * MB);
    u16* w1T  = (u16*)(ws + 128 * MB);   // [2048,1024]
    u16* w2T  = (u16*)(ws + 132 * MB);   // [256,2048]
    u16* wd1T = (u16*)(ws + 133 * MB);   // [2048,256]
    u16* wd2T = (u16*)(ws + 134 * MB);   // [1024,2048]
    float* enorm = (float*)(ws + 138 * MB);
    u64*   keys  = (u64*)(ws + 138 * MB + 131072);
    double* accs = (double*)(ws + 138 * MB + 262144);
    int*   cnt   = (int*)(ws + 138 * MB + 262144 + 4096);   // HQ*128 ints

    // fused: enorm + (-2E bf16) + keys/accs/cnt init
    enorm_k<<<HQ * VOCAB / 4, 256, 0, stream>>>(cb, enorm, cbb, keys, accs, cnt);

    // all weight transposes in one launch + x conversion
    tpose4_k<<<5120, 256, 0, stream>>>(enc_w1, w1T, enc_w2, w2T,
                                       dec_w1, wd1T, dec_w2, wd2T);
    f2bf_k<<<(int)((size_t)N_ROWS * OBS / 1024), 256, 0, stream>>>(x, xbf);

    // encoder: GEMM1 -> LN+ReLU -> GEMM2 (64-tile)
    mfma_gemm_k<0><<<dim3(N_ROWS / 128, HID / 128), 256, 0, stream>>>(
        xbf, w1T, enc_b1, hbuf, nullptr, nullptr, OBS, HID);
    ln_relu_bf_k<<<N_ROWS, 256, 0, stream>>>(hbuf, ln_g, ln_b);
    gemm2_k<<<dim3(N_ROWS / 64, LAT / 64), 256, 0, stream>>>(
        hbuf, w2T, enc_b2, latent, resid, rbf);

    // VQ levels: dist + fused vq_update tail
    for (int l = 0; l < HQ; ++l) {
        const u16*   Bn = cbb + (size_t)l * VOCAB * LAT;
        const float* en = enorm + (size_t)l * VOCAB;
        const float* E  = cb + (size_t)l * VOCAB * LAT;
        int* cl = cnt + l * 128;
        if (l < HQ - 1)
            dist_mfma_k<false><<<dim3(N_ROWS / 128, VOCAB / 128), 256, 0, stream>>>(
                rbf, Bn, en, keys, resid, rbf, nullptr, E, cl, accs);
        else
            dist_mfma_k<true><<<dim3(N_ROWS / 128, VOCAB / 128), 256, 0, stream>>>(
                rbf, Bn, en, keys, resid, qbf, latent, E, cl, accs);
    }

    // decoder GEMM3 -> GEMM4(+loss)
    mfma_gemm_k<1><<<dim3(N_ROWS / 128, HID / 128), 256, 0, stream>>>(
        qbf, wd1T, dec_b1, hbuf, nullptr, nullptr, LAT, HID);
    mfma_gemm_k<3><<<dim3(N_ROWS / 128, OBS / 128), 256, 0, stream>>>(
        hbuf, wd2T, dec_b2, nullptr, x, accs + 1, HID, OBS);

    finalize_k<<<1, 1, 0, stream>>>(accs, (float*)d_out);
}

// Round 10
// 1372.945 us; speedup vs baseline: 1.9354x; 1.9354x over previous
//
#include <hip/hip_runtime.h>

#define N_ROWS 16384
#define OBS    1024
#define HID    2048
#define LAT    256
#define VOCAB  8192
#define HQ     4
#define LN_EPS 1e-5f

typedef unsigned short u16;
typedef unsigned long long u64;
typedef __bf16 bf16x8 __attribute__((ext_vector_type(8)));
typedef float  f32x4  __attribute__((ext_vector_type(4)));

static __device__ __forceinline__ unsigned int float_to_ordered(float f) {
    unsigned int u = __float_as_uint(f);
    return (u & 0x80000000u) ? ~u : (u | 0x80000000u);
}
// fp32 -> bf16 round-to-nearest-even
static __device__ __forceinline__ u16 f2bf(float f) {
    unsigned int u = __float_as_uint(f);
    unsigned int r = u + 0x7FFFu + ((u >> 16) & 1u);
    return (u16)(r >> 16);
}
static __device__ __forceinline__ float bf2f(u16 u) {
    return __uint_as_float((unsigned int)u << 16);
}

#define GL2LDS(gp, lp) __builtin_amdgcn_global_load_lds( \
    (const __attribute__((address_space(1))) void*)(gp), \
    (__attribute__((address_space(3))) void*)(lp), 16, 0, 0)

// ---------------------------------------------------------------------------
// bf16 MFMA GEMM, 128x128 tile, C = A @ B^T + bias. (verified rounds 3-8)
// EPI 0: store bf16 C.  1: relu + store bf16 C.  3: fused loss, no store.
// ---------------------------------------------------------------------------
template<int EPI>
__global__ __launch_bounds__(256, 4) void mfma_gemm_k(
    const u16* __restrict__ Abf, const u16* __restrict__ Bbf,
    const float* __restrict__ bias,
    u16* __restrict__ Cbf,
    const float* __restrict__ X, double* __restrict__ lacc,
    int K, int Nd)
{
    __shared__ u16 As[128 * 64];
    __shared__ u16 Bs[128 * 64];

    const int tid  = threadIdx.x;
    const int wv   = tid >> 6, lane = tid & 63;
    const int wm   = wv & 1,   wn   = wv >> 1;
    const int m_   = lane & 15, g   = lane >> 4;
    const int m0   = blockIdx.x * 128;
    const int n0   = blockIdx.y * 128;

    f32x4 acc[4][4];
#pragma unroll
    for (int i = 0; i < 4; ++i)
#pragma unroll
        for (int j = 0; j < 4; ++j)
            acc[i][j] = f32x4{0.f, 0.f, 0.f, 0.f};

    const u16* Ablk = Abf + (size_t)m0 * K;
    const u16* Bblk = Bbf + (size_t)n0 * K;

    for (int k0 = 0; k0 < K; k0 += 64) {
#pragma unroll
        for (int c = 0; c < 4; ++c) {
            const int ci = (wv * 4 + c) * 64 + lane;
            const int r  = ci >> 3;
            const int cc = ci & 7;
            const int kc = (cc ^ (r & 7)) << 3;
            GL2LDS(Ablk + (size_t)r * K + k0 + kc, As + (wv * 4 + c) * 512);
            GL2LDS(Bblk + (size_t)r * K + k0 + kc, Bs + (wv * 4 + c) * 512);
        }
        __syncthreads();
#pragma unroll
        for (int ks = 0; ks < 2; ++ks) {
            const int ccw = ks * 4 + g;
            const int sw  = (ccw ^ (m_ & 7)) << 3;
            bf16x8 af[4], bfr[4];
#pragma unroll
            for (int t = 0; t < 4; ++t) {
                af[t]  = *(const bf16x8*)&As[(wm * 64 + t * 16 + m_) * 64 + sw];
                bfr[t] = *(const bf16x8*)&Bs[(wn * 64 + t * 16 + m_) * 64 + sw];
            }
#pragma unroll
            for (int mi = 0; mi < 4; ++mi)
#pragma unroll
                for (int ni = 0; ni < 4; ++ni)
                    acc[mi][ni] = __builtin_amdgcn_mfma_f32_16x16x32_bf16(
                        af[mi], bfr[ni], acc[mi][ni], 0, 0, 0);
        }
        __syncthreads();
    }

    float bs[4];
#pragma unroll
    for (int ni = 0; ni < 4; ++ni) bs[ni] = bias[n0 + wn * 64 + ni * 16 + m_];

    if constexpr (EPI == 3) {
        float lsum = 0.f;
#pragma unroll
        for (int mi = 0; mi < 4; ++mi)
#pragma unroll
            for (int j = 0; j < 4; ++j) {
                const int row = m0 + wm * 64 + mi * 16 + g * 4 + j;
#pragma unroll
                for (int ni = 0; ni < 4; ++ni) {
                    const int col = n0 + wn * 64 + ni * 16 + m_;
                    float r = acc[mi][ni][j] + bs[ni] - X[(size_t)row * Nd + col];
                    lsum = fmaf(r, r, lsum);
                }
            }
#pragma unroll
        for (int off = 32; off >= 1; off >>= 1) lsum += __shfl_xor(lsum, off);
        __shared__ float red[4];
        if (lane == 0) red[wv] = lsum;
        __syncthreads();
        if (tid == 0)
            atomicAdd(lacc, (double)(red[0] + red[1] + red[2] + red[3]));
    } else {
#pragma unroll
        for (int mi = 0; mi < 4; ++mi)
#pragma unroll
            for (int j = 0; j < 4; ++j) {
                const int row = m0 + wm * 64 + mi * 16 + g * 4 + j;
#pragma unroll
                for (int ni = 0; ni < 4; ++ni) {
                    const int col = n0 + wn * 64 + ni * 16 + m_;
                    float v = acc[mi][ni][j] + bs[ni];
                    if constexpr (EPI == 1) v = fmaxf(v, 0.f);
                    Cbf[(size_t)row * Nd + col] = f2bf(v);
                }
            }
    }
}

// ---------------------------------------------------------------------------
// GEMM2 dedicated kernel: 64x64 tile (1024 blocks = 4/CU).
// latent = h @ w2T^T + b2; writes fp32 latent + fp32 resid + bf16 rbf.
// ---------------------------------------------------------------------------
__global__ __launch_bounds__(256, 4) void gemm2_k(
    const u16* __restrict__ Abf, const u16* __restrict__ Bbf,
    const float* __restrict__ bias,
    float* __restrict__ lat, float* __restrict__ resid, u16* __restrict__ rbf)
{
    __shared__ u16 As[64 * 64];
    __shared__ u16 Bs[64 * 64];

    const int tid = threadIdx.x;
    const int wv  = tid >> 6, lane = tid & 63;
    const int wm  = wv & 1,   wn   = wv >> 1;
    const int m_  = lane & 15, g   = lane >> 4;
    const int m0  = blockIdx.x * 64;
    const int n0  = blockIdx.y * 64;

    f32x4 acc[2][2];
#pragma unroll
    for (int i = 0; i < 2; ++i)
#pragma unroll
        for (int j = 0; j < 2; ++j)
            acc[i][j] = f32x4{0.f, 0.f, 0.f, 0.f};

    const u16* Ablk = Abf + (size_t)m0 * HID;
    const u16* Bblk = Bbf + (size_t)n0 * HID;

    for (int k0 = 0; k0 < HID; k0 += 64) {
#pragma unroll
        for (int c = 0; c < 2; ++c) {
            const int ci = (wv * 2 + c) * 64 + lane;
            const int r  = ci >> 3;
            const int cc = ci & 7;
            const int kc = (cc ^ (r & 7)) << 3;
            GL2LDS(Ablk + (size_t)r * HID + k0 + kc, As + (wv * 2 + c) * 512);
            GL2LDS(Bblk + (size_t)r * HID + k0 + kc, Bs + (wv * 2 + c) * 512);
        }
        __syncthreads();
#pragma unroll
        for (int ks = 0; ks < 2; ++ks) {
            const int ccw = ks * 4 + g;
            const int sw  = (ccw ^ (m_ & 7)) << 3;
            bf16x8 af[2], bfr[2];
#pragma unroll
            for (int t = 0; t < 2; ++t) {
                af[t]  = *(const bf16x8*)&As[(wm * 32 + t * 16 + m_) * 64 + sw];
                bfr[t] = *(const bf16x8*)&Bs[(wn * 32 + t * 16 + m_) * 64 + sw];
            }
#pragma unroll
            for (int mi = 0; mi < 2; ++mi)
#pragma unroll
                for (int ni = 0; ni < 2; ++ni)
                    acc[mi][ni] = __builtin_amdgcn_mfma_f32_16x16x32_bf16(
                        af[mi], bfr[ni], acc[mi][ni], 0, 0, 0);
        }
        __syncthreads();
    }

#pragma unroll
    for (int mi = 0; mi < 2; ++mi)
#pragma unroll
        for (int j = 0; j < 4; ++j) {
            const int row = m0 + wm * 32 + mi * 16 + g * 4 + j;
#pragma unroll
            for (int ni = 0; ni < 2; ++ni) {
                const int col = n0 + wn * 32 + ni * 16 + m_;
                float v = acc[mi][ni][j] + bias[col];
                lat  [(size_t)row * LAT + col] = v;
                resid[(size_t)row * LAT + col] = v;
                rbf  [(size_t)row * LAT + col] = f2bf(v);
            }
        }
}

// ---------------------------------------------------------------------------
// All 4 weight transposes + x->bf16 conversion in ONE launch.
// Blocks 0..5119: transpose W fp32 [K,N] -> Wt bf16 [N,K].
// Blocks 5120..21503: convert x (16M floats, 1024/block).
// ---------------------------------------------------------------------------
__global__ __launch_bounds__(256) void tpose4_k(
    const float* __restrict__ W0, u16* __restrict__ T0,
    const float* __restrict__ W1, u16* __restrict__ T1,
    const float* __restrict__ W2, u16* __restrict__ T2,
    const float* __restrict__ W3, u16* __restrict__ T3,
    const float* __restrict__ x, u16* __restrict__ xbf)
{
    __shared__ u16 t[32][33];
    const int bid = blockIdx.x;
    if (bid >= 5120) {
        size_t i = ((size_t)(bid - 5120) * 256 + threadIdx.x) * 4;
        float4 v = *(const float4*)(x + i);
        ushort4 o;
        o.x = f2bf(v.x); o.y = f2bf(v.y); o.z = f2bf(v.z); o.w = f2bf(v.w);
        *(ushort4*)(xbf + i) = o;
        return;
    }
    const float* W; u16* T; int K, N, r;
    if (bid < 2048)      { W = W0; T = T0; K = OBS; N = HID; r = bid; }
    else if (bid < 2560) { W = W1; T = T1; K = HID; N = LAT; r = bid - 2048; }
    else if (bid < 3072) { W = W2; T = T2; K = LAT; N = HID; r = bid - 2560; }
    else                 { W = W3; T = T3; K = HID; N = OBS; r = bid - 3072; }
    const int nb = N >> 5;
    const int n0 = (r % nb) * 32, k0 = (r / nb) * 32;
    const int lx = threadIdx.x & 31, ly = threadIdx.x >> 5;
#pragma unroll
    for (int i = 0; i < 4; ++i)
        t[ly + 8 * i][lx] = f2bf(W[(size_t)(k0 + ly + 8 * i) * N + n0 + lx]);
    __syncthreads();
#pragma unroll
    for (int i = 0; i < 4; ++i)
        T[(size_t)(n0 + ly + 8 * i) * K + k0 + lx] = t[lx][ly + 8 * i];
}

// ---------------------------------------------------------------------------
// LayerNorm + ReLU in place on bf16 h (fp32 math), one block per row of 2048.
// ---------------------------------------------------------------------------
__device__ __forceinline__ float block_reduce_bcast(float v, float* scratch) {
#pragma unroll
    for (int off = 32; off >= 1; off >>= 1) v += __shfl_xor(v, off);
    const int tid = threadIdx.x;
    __syncthreads();
    if ((tid & 63) == 0) scratch[tid >> 6] = v;
    __syncthreads();
    return scratch[0] + scratch[1] + scratch[2] + scratch[3];
}

__global__ __launch_bounds__(256) void ln_relu_bf_k(
    u16* __restrict__ h, const float* __restrict__ g, const float* __restrict__ b)
{
    __shared__ float scratch[4];
    const int tid = threadIdx.x;
    u16* hp = h + (size_t)blockIdx.x * HID + tid * 8;

    ushort4 r0 = *(const ushort4*)hp;
    ushort4 r1 = *(const ushort4*)(hp + 4);
    float v[8] = {bf2f(r0.x), bf2f(r0.y), bf2f(r0.z), bf2f(r0.w),
                  bf2f(r1.x), bf2f(r1.y), bf2f(r1.z), bf2f(r1.w)};

    float s = 0.f;
#pragma unroll
    for (int e = 0; e < 8; ++e) s += v[e];
    const float mu = block_reduce_bcast(s, scratch) * (1.f / HID);

    float vs = 0.f;
#pragma unroll
    for (int e = 0; e < 8; ++e) { float d = v[e] - mu; vs = fmaf(d, d, vs); }
    const float var = block_reduce_bcast(vs, scratch) * (1.f / HID);
    const float rs = rsqrtf(var + LN_EPS);

    ushort4 o0, o1;
#pragma unroll
    for (int e = 0; e < 8; ++e) {
        const int col = tid * 8 + e;
        float w = (v[e] - mu) * rs * g[col] + b[col];
        w = fmaxf(w, 0.f);
        u16 bb = f2bf(w);
        if (e < 4) ((u16*)&o0)[e] = bb; else ((u16*)&o1)[e - 4] = bb;
    }
    *(ushort4*)hp = o0;
    *(ushort4*)(hp + 4) = o1;
}

// ---------------------------------------------------------------------------
// Fused codebook pass: exact fp32 norms + bf16(-2E) copy + keys/accs init.
// ---------------------------------------------------------------------------
__global__ __launch_bounds__(256) void enorm_k(
    const float* __restrict__ cb, float* __restrict__ enorm,
    u16* __restrict__ cbb, u64* __restrict__ keys, double* __restrict__ accs)
{
    if (blockIdx.x < 64) keys[blockIdx.x * 256 + threadIdx.x] = ~0ull;
    if (blockIdx.x == 64 && threadIdx.x < 2) accs[threadIdx.x] = 0.0;
    const int row  = blockIdx.x * 4 + (threadIdx.x >> 6);
    const int lane = threadIdx.x & 63;
    const size_t off = (size_t)row * LAT + lane * 4;
    float4 v = *(const float4*)(cb + off);
    ushort4 o;
    o.x = f2bf(-2.f * v.x); o.y = f2bf(-2.f * v.y);
    o.z = f2bf(-2.f * v.z); o.w = f2bf(-2.f * v.w);
    *(ushort4*)(cbb + off) = o;
    float s = v.x * v.x + v.y * v.y + v.z * v.z + v.w * v.w;
#pragma unroll
    for (int off2 = 32; off2 >= 1; off2 >>= 1) s += __shfl_xor(s, off2);
    if (lane == 0) enorm[row] = s;
}

// ---------------------------------------------------------------------------
// Distance + argmin via bf16 MFMA — round-8 core with shk ALIASED onto As
// (dead after the K-loop) -> LDS exactly 32 KB -> 5 blocks/CU with
// launch_bounds(256,5) (VGPR cap 102; kernel uses ~64).
// ---------------------------------------------------------------------------
__global__ __launch_bounds__(256, 5) void dist_mfma_k(
    const u16* __restrict__ Abf, const u16* __restrict__ Bneg2,
    const float* __restrict__ enorm, u64* __restrict__ keys)
{
    __shared__ u16 As[128 * 64];
    __shared__ u16 Bs[128 * 64];
    u64 (*shk)[2] = (u64(*)[2])As;     // alias: As dead after K-loop barrier

    const int tid  = threadIdx.x;
    const int wv   = tid >> 6, lane = tid & 63;
    const int wm   = wv & 1,   wn   = wv >> 1;
    const int m_   = lane & 15, g   = lane >> 4;
    const int m0   = blockIdx.x * 128;
    const int n0   = blockIdx.y * 128;

    f32x4 acc[4][4];
#pragma unroll
    for (int ni = 0; ni < 4; ++ni) {
        const float en = enorm[n0 + wn * 64 + ni * 16 + m_];
#pragma unroll
        for (int mi = 0; mi < 4; ++mi)
            acc[mi][ni] = f32x4{en, en, en, en};
    }

    const u16* Ablk = Abf   + (size_t)m0 * LAT;
    const u16* Bblk = Bneg2 + (size_t)n0 * LAT;

    for (int k0 = 0; k0 < LAT; k0 += 64) {
#pragma unroll
        for (int c = 0; c < 4; ++c) {
            const int ci = (wv * 4 + c) * 64 + lane;
            const int r  = ci >> 3;
            const int cc = ci & 7;
            const int kc = (cc ^ (r & 7)) << 3;
            GL2LDS(Ablk + (size_t)r * LAT + k0 + kc, As + (wv * 4 + c) * 512);
            GL2LDS(Bblk + (size_t)r * LAT + k0 + kc, Bs + (wv * 4 + c) * 512);
        }
        __syncthreads();
#pragma unroll
        for (int ks = 0; ks < 2; ++ks) {
            const int ccw = ks * 4 + g;
            const int sw  = (ccw ^ (m_ & 7)) << 3;
            bf16x8 af[4], bfr[4];
#pragma unroll
            for (int t = 0; t < 4; ++t) {
                af[t]  = *(const bf16x8*)&As[(wm * 64 + t * 16 + m_) * 64 + sw];
                bfr[t] = *(const bf16x8*)&Bs[(wn * 64 + t * 16 + m_) * 64 + sw];
            }
#pragma unroll
            for (int mi = 0; mi < 4; ++mi)
#pragma unroll
                for (int ni = 0; ni < 4; ++ni)
                    acc[mi][ni] = __builtin_amdgcn_mfma_f32_16x16x32_bf16(
                        af[mi], bfr[ni], acc[mi][ni], 0, 0, 0);
        }
        __syncthreads();
    }

#pragma unroll
    for (int mi = 0; mi < 4; ++mi)
#pragma unroll
        for (int j = 0; j < 4; ++j) {
            float bs_ = acc[mi][0][j];
            int   bi_ = n0 + wn * 64 + m_;
#pragma unroll
            for (int ni = 1; ni < 4; ++ni) {
                const float s = acc[mi][ni][j];
                const int   v = n0 + wn * 64 + ni * 16 + m_;
                if (s < bs_) { bs_ = s; bi_ = v; }
            }
            u64 best = ((u64)float_to_ordered(bs_) << 32) | (unsigned)bi_;
#pragma unroll
            for (int mask = 1; mask <= 8; mask <<= 1) {
                u64 o = __shfl_xor(best, mask);
                best = o < best ? o : best;
            }
            if (m_ == 0) shk[wm * 64 + mi * 16 + g * 4 + j][wn] = best;
        }
    __syncthreads();
    if (tid < 128) {
        u64 a = shk[tid][0], b = shk[tid][1];
        atomicMin(&keys[m0 + tid], a < b ? a : b);
    }
}

// ---------------------------------------------------------------------------
// Gather chosen code (fp32 exact), update residual, accumulate
// sum(resid_new^2), reset keys for the next level.
// LAST: skip resid/rbf stores, write qbf = f2bf(latent - resid_new) instead.
// ---------------------------------------------------------------------------
template<bool LAST>
__global__ __launch_bounds__(256) void vq_update_k(
    float* __restrict__ resid, u16* __restrict__ aux,   // aux = rbf or qbf
    const float* __restrict__ latent,
    const float* __restrict__ E,
    u64* __restrict__ keys, double* __restrict__ acc)
{
    __shared__ float red[4];
    const int tid = threadIdx.x;
    const int base = blockIdx.x * 16;
    float lsum = 0.f;
    for (int r = 0; r < 16; ++r) {
        const int row = base + r;
        const int idx = (int)(keys[row] & 0xFFFFFFFFull);
        const float q = E[(size_t)idx * LAT + tid];
        float v = resid[(size_t)row * LAT + tid] - q;
        if constexpr (LAST) {
            aux[(size_t)row * LAT + tid] =
                f2bf(latent[(size_t)row * LAT + tid] - v);
        } else {
            resid[(size_t)row * LAT + tid] = v;
            aux[(size_t)row * LAT + tid] = f2bf(v);
        }
        lsum = fmaf(v, v, lsum);
    }
    if (!LAST && tid < 16) keys[base + tid] = ~0ull;
#pragma unroll
    for (int off = 32; off >= 1; off >>= 1) lsum += __shfl_xor(lsum, off);
    if ((tid & 63) == 0) red[tid >> 6] = lsum;
    __syncthreads();
    if (tid == 0) atomicAdd(acc, (double)(red[0] + red[1] + red[2] + red[3]));
}

__global__ void finalize_k(const double* __restrict__ acc, float* __restrict__ out) {
    double total = 1.5 * acc[0] / (double)((size_t)N_ROWS * LAT)
                 + 0.5 * acc[1] / (double)((size_t)N_ROWS * OBS);
    out[0] = (float)total;
}

// ---------------------------------------------------------------------------
extern "C" void kernel_launch(void* const* d_in, const int* in_sizes, int n_in,
                              void* d_out, int out_size, void* d_ws, size_t ws_size,
                              hipStream_t stream)
{
    const float* x      = (const float*)d_in[0];
    const float* cb     = (const float*)d_in[1];
    const float* enc_w1 = (const float*)d_in[2];
    const float* enc_b1 = (const float*)d_in[3];
    const float* ln_g   = (const float*)d_in[4];
    const float* ln_b   = (const float*)d_in[5];
    const float* enc_w2 = (const float*)d_in[6];
    const float* enc_b2 = (const float*)d_in[7];
    const float* dec_w1 = (const float*)d_in[8];
    const float* dec_b1 = (const float*)d_in[9];
    const float* dec_w2 = (const float*)d_in[10];
    const float* dec_b2 = (const float*)d_in[11];

    char* ws = (char*)d_ws;
    const size_t MB = 1ull << 20;
    u16* hbuf = (u16*)ws;                          // 0-64MB: h_bf then dh_bf
    u16* cbb  = (u16*)(ws + 64 * MB);              // -2E bf16, live all launch
    u16* rbf  = (u16*)(ws + 80 * MB);
    u16* qbf  = (u16*)(ws + 88 * MB);
    u16* xbf  = (u16*)(ws + 96 * MB);              // overlaps latent (dead by GEMM2)
    float* latent = (float*)(ws + 96 * MB);
    float* resid  = (float*)(ws + 112 * MB);
    u16* w1T  = (u16*)(ws + 128 * MB);   // [2048,1024]
    u16* w2T  = (u16*)(ws + 132 * MB);   // [256,2048]
    u16* wd1T = (u16*)(ws + 133 * MB);   // [2048,256]
    u16* wd2T = (u16*)(ws + 134 * MB);   // [1024,2048]
    float* enorm = (float*)(ws + 138 * MB);
    u64*   keys  = (u64*)(ws + 138 * MB + 131072);
    double* accs = (double*)(ws + 138 * MB + 262144);

    // fused: enorm + (-2E bf16) + keys/accs init
    enorm_k<<<HQ * VOCAB / 4, 256, 0, stream>>>(cb, enorm, cbb, keys, accs);

    // all weight transposes + x conversion in one launch
    tpose4_k<<<5120 + 16384, 256, 0, stream>>>(enc_w1, w1T, enc_w2, w2T,
                                               dec_w1, wd1T, dec_w2, wd2T,
                                               x, xbf);

    // encoder: GEMM1 -> LN+ReLU -> GEMM2 (64-tile)
    mfma_gemm_k<0><<<dim3(N_ROWS / 128, HID / 128), 256, 0, stream>>>(
        xbf, w1T, enc_b1, hbuf, nullptr, nullptr, OBS, HID);
    ln_relu_bf_k<<<N_ROWS, 256, 0, stream>>>(hbuf, ln_g, ln_b);
    gemm2_k<<<dim3(N_ROWS / 64, LAT / 64), 256, 0, stream>>>(
        hbuf, w2T, enc_b2, latent, resid, rbf);

    for (int l = 0; l < HQ; ++l) {
        dist_mfma_k<<<dim3(N_ROWS / 128, VOCAB / 128), 256, 0, stream>>>(
            rbf, cbb + (size_t)l * VOCAB * LAT, enorm + (size_t)l * VOCAB, keys);
        if (l < HQ - 1)
            vq_update_k<false><<<N_ROWS / 16, 256, 0, stream>>>(
                resid, rbf, nullptr, cb + (size_t)l * VOCAB * LAT, keys, accs);
        else
            vq_update_k<true><<<N_ROWS / 16, 256, 0, stream>>>(
                resid, qbf, latent, cb + (size_t)l * VOCAB * LAT, keys, accs);
    }

    // decoder GEMM3 -> GEMM4(+loss)
    mfma_gemm_k<1><<<dim3(N_ROWS / 128, HID / 128), 256, 0, stream>>>(
        qbf, wd1T, dec_b1, hbuf, nullptr, nullptr, LAT, HID);
    mfma_gemm_k<3><<<dim3(N_ROWS / 128, OBS / 128), 256, 0, stream>>>(
        hbuf, wd2T, dec_b2, nullptr, x, accs + 1, HID, OBS);

    finalize_k<<<1, 1, 0, stream>>>(accs, (float*)d_out);
}